// Round 1
// baseline (635.701 us; speedup 1.0000x reference)
//
#include <hip/hip_runtime.h>
#include <math.h>

#define BATCH 8
#define IH 384
#define IW 512
#define NPIX (IH*IW)          // 196608
#define BN (BATCH*NPIX)       // 1572864

__device__ __forceinline__ float sigmoidf_(float x){ return 1.0f/(1.0f+expf(-x)); }

__device__ __forceinline__ float block_reduce_sum(float v){
    __shared__ float s[8];
    #pragma unroll
    for (int off=32; off>0; off>>=1) v += __shfl_down(v, off);
    int lane = threadIdx.x & 63, wid = threadIdx.x >> 6;
    if (lane==0) s[wid] = v;
    __syncthreads();
    float t = 0.f;
    if (wid==0){
        int nw = (blockDim.x+63)>>6;
        t = (lane < nw) ? s[lane] : 0.f;
        #pragma unroll
        for (int off=4; off>0; off>>=1) t += __shfl_down(t, off);
    }
    __syncthreads();
    return t;
}

// Kernel 1: flows = mean + exp(lv/2)*noise; accumulate entropy-sum and epe-sum.
__global__ void flows_kernel(const float* __restrict__ meanf, const float* __restrict__ log_varf,
                             const float* __restrict__ meanb, const float* __restrict__ log_varb,
                             const float* __restrict__ target,
                             const float* __restrict__ noise_f, const float* __restrict__ noise_b,
                             float* __restrict__ flowf, float* __restrict__ flowb,
                             float* __restrict__ acc)
{
    int t = blockIdx.x*blockDim.x + threadIdx.x;
    float ent = 0.f, epe = 0.f;
    if (t < BN){
        int b = t / NPIX, p = t - b*NPIX;
        size_t i0 = (size_t)b*2*NPIX + p, i1 = i0 + NPIX;
        float lvf0 = log_varf[i0], lvf1 = log_varf[i1];
        float lvb0 = log_varb[i0], lvb1 = log_varb[i1];
        flowf[i0] = meanf[i0] + expf(0.5f*lvf0)*noise_f[i0];
        flowf[i1] = meanf[i1] + expf(0.5f*lvf1)*noise_f[i1];
        flowb[i0] = meanb[i0] + expf(0.5f*lvb0)*noise_b[i0];
        flowb[i1] = meanb[i1] + expf(0.5f*lvb1)*noise_b[i1];
        ent = lvf0 + lvf1 + lvb0 + lvb1;
        float d0 = meanf[i0] - target[i0];
        float d1 = meanf[i1] - target[i1];
        epe = sqrtf(d0*d0 + d1*d1);
    }
    float s = block_reduce_sum(ent);
    if (threadIdx.x == 0) atomicAdd(&acc[1], s);
    float s2 = block_reduce_sum(epe);
    if (threadIdx.x == 0) atomicAdd(&acc[2], s2);
}

// Kernel 2: one direction's warp + mask + (mask_term, data, smooth, fb) energy terms.
// Writes img_b warped by flow_a into warp_out, and mask (border*occ) into mask_out.
__global__ void warp_terms_kernel(const float* __restrict__ flow_a, const float* __restrict__ flow_b,
                                  const float* __restrict__ img_a,  const float* __restrict__ img_b,
                                  float* __restrict__ warp_out, float* __restrict__ mask_out,
                                  float* __restrict__ acc)
{
    int t = blockIdx.x*blockDim.x + threadIdx.x;
    float local = 0.f;
    if (t < BN){
        int b = t / NPIX, p = t - b*NPIX;
        int h = p / IW, w = p - h*IW;
        const float* fa = flow_a + (size_t)b*2*NPIX;
        float fax = fa[p], fay = fa[NPIX + p];

        // border mask
        float Xp = (float)w + fax;
        float Yp = (float)h + fay;
        float mx = sigmoidf_(Xp + 0.5f) * (1.f - sigmoidf_(Xp - ((float)IW - 0.5f)));
        float my = sigmoidf_(Yp + 0.5f) * (1.f - sigmoidf_(Yp - ((float)IH - 0.5f)));
        float bm = mx * my;

        // bilinear taps (shared by flow_b and img_b)
        float x0f = floorf(Xp), y0f = floorf(Yp);
        float wx1 = Xp - x0f, wy1 = Yp - y0f;
        float wx0 = 1.f - wx1, wy0 = 1.f - wy1;
        int   idx[4]; float wt[4];
        {
            float xs[4] = {x0f, x0f + 1.f, x0f,       x0f + 1.f};
            float ys[4] = {y0f, y0f,       y0f + 1.f, y0f + 1.f};
            float wsx[4] = {wx0*wy0, wx1*wy0, wx0*wy1, wx1*wy1};
            #pragma unroll
            for (int k = 0; k < 4; ++k){
                bool valid = (xs[k] >= 0.f) && (xs[k] <= (float)(IW-1)) &&
                             (ys[k] >= 0.f) && (ys[k] <= (float)(IH-1));
                float xc = fminf(fmaxf(xs[k], 0.f), (float)(IW-1));
                float yc = fminf(fmaxf(ys[k], 0.f), (float)(IH-1));
                idx[k] = (int)yc * IW + (int)xc;
                wt[k]  = valid ? wsx[k] : 0.f;
            }
        }

        // flow_b warped
        const float* fb = flow_b + (size_t)b*2*NPIX;
        float fbwx = wt[0]*fb[idx[0]] + wt[1]*fb[idx[1]] + wt[2]*fb[idx[2]] + wt[3]*fb[idx[3]];
        float fbwy = wt[0]*fb[NPIX+idx[0]] + wt[1]*fb[NPIX+idx[1]]
                   + wt[2]*fb[NPIX+idx[2]] + wt[3]*fb[NPIX+idx[3]];

        // img_b warped (3 channels), stored for the grad pass
        const float* ib = img_b + (size_t)b*3*NPIX;
        float iw[3];
        #pragma unroll
        for (int c = 0; c < 3; ++c){
            const float* s = ib + (size_t)c*NPIX;
            iw[c] = wt[0]*s[idx[0]] + wt[1]*s[idx[1]] + wt[2]*s[idx[2]] + wt[3]*s[idx[3]];
            warp_out[(size_t)b*3*NPIX + (size_t)c*NPIX + p] = iw[c];
        }

        // occlusion + mask
        float mag = fax*fax + fay*fay + fbwx*fbwx + fbwy*fbwy;
        float dfx = fax + fbwx, dfy = fay + fbwy;
        float D = dfx*dfx + dfy*dfy;
        float occ = 1.f - sigmoidf_(D - (0.01f*mag + 0.5f));
        float mask = bm * occ;
        mask_out[t] = mask;

        // mask term
        local += (1.f - mask);

        // data term
        const float* ia = img_a + (size_t)b*3*NPIX;
        float A = 0.f;
        #pragma unroll
        for (int c = 0; c < 3; ++c){
            float d = ia[(size_t)c*NPIX + p] - iw[c];
            A += d*d;
        }
        local += sqrtf(A + 1e-5f) * mask;

        // fb term
        local += sqrtf(D + 1e-5f) * mask;

        // smoothness term
        float Bt = 0.f;
        if (w < IW-1){
            float d0 = fa[p+1] - fax;
            float d1 = fa[NPIX + p+1] - fay;
            Bt += d0*d0 + d1*d1;
        }
        if (h < IH-1){
            float d0 = fa[p+IW] - fax;
            float d1 = fa[NPIX + p+IW] - fay;
            Bt += d0*d0 + d1*d1;
        }
        local += sqrtf(Bt + 1e-5f);
    }
    float s = block_reduce_sum(local);
    if (threadIdx.x == 0) atomicAdd(&acc[0], s);
}

// Kernel 3: gradient-constancy term using materialized warp image + mask.
// 5-tap cross-correlation taps: (-1/12, 2/3, 0, -2/3, 1/12), zero padding.
__global__ void grad_kernel(const float* __restrict__ img_a, const float* __restrict__ warp,
                            const float* __restrict__ mask, float* __restrict__ acc)
{
    const float K0 = -1.f/12.f, K1 = 2.f/3.f, K3 = -2.f/3.f, K4 = 1.f/12.f;
    int t = blockIdx.x*blockDim.x + threadIdx.x;
    float local = 0.f;
    if (t < BN){
        int b = t / NPIX, p = t - b*NPIX;
        int h = p / IW, w = p - h*IW;
        float Ct = 0.f;
        #pragma unroll
        for (int c = 0; c < 3; ++c){
            const float* A_ = img_a + (size_t)b*3*NPIX + (size_t)c*NPIX;
            const float* W_ = warp  + (size_t)b*3*NPIX + (size_t)c*NPIX;
            float gxa = 0.f, gxw = 0.f;
            if (w >= 2)    { gxa += K0*A_[p-2];    gxw += K0*W_[p-2]; }
            if (w >= 1)    { gxa += K1*A_[p-1];    gxw += K1*W_[p-1]; }
            if (w <= IW-2) { gxa += K3*A_[p+1];    gxw += K3*W_[p+1]; }
            if (w <= IW-3) { gxa += K4*A_[p+2];    gxw += K4*W_[p+2]; }
            float d = gxa - gxw; Ct += d*d;
            float gya = 0.f, gyw = 0.f;
            if (h >= 2)    { gya += K0*A_[p-2*IW]; gyw += K0*W_[p-2*IW]; }
            if (h >= 1)    { gya += K1*A_[p-IW];   gyw += K1*W_[p-IW]; }
            if (h <= IH-2) { gya += K3*A_[p+IW];   gyw += K3*W_[p+IW]; }
            if (h <= IH-3) { gya += K4*A_[p+2*IW]; gyw += K4*W_[p+2*IW]; }
            d = gya - gyw; Ct += d*d;
        }
        local = sqrtf(Ct + 1e-5f) * mask[t];
    }
    float s = block_reduce_sum(local);
    if (threadIdx.x == 0) atomicAdd(&acc[0], s);
}

__global__ void finalize_kernel(const float* __restrict__ acc, float* __restrict__ out)
{
    // acc[0]=energy sum (all terms, both directions), acc[1]=sum(log_varf)+sum(log_varb), acc[2]=epe sum
    out[0] = acc[0] / (float)BATCH - acc[1] / (2.f * (float)BATCH);
    out[1] = acc[2] / ((float)BATCH * (float)NPIX);
}

extern "C" void kernel_launch(void* const* d_in, const int* in_sizes, int n_in,
                              void* d_out, int out_size, void* d_ws, size_t ws_size,
                              hipStream_t stream)
{
    const float* meanf    = (const float*)d_in[0];
    const float* log_varf = (const float*)d_in[1];
    const float* meanb    = (const float*)d_in[2];
    const float* log_varb = (const float*)d_in[3];
    const float* img1     = (const float*)d_in[4];
    const float* img2     = (const float*)d_in[5];
    const float* target   = (const float*)d_in[6];
    const float* noise_f  = (const float*)d_in[7];
    const float* noise_b  = (const float*)d_in[8];

    float* ws    = (float*)d_ws;
    float* acc   = ws;                 // 16 floats
    float* flowf = ws + 16;            // 2*BN
    float* flowb = flowf + 2*(size_t)BN;   // 2*BN
    float* warp  = flowb + 2*(size_t)BN;   // 3*BN (reused per direction)
    float* maskb = warp  + 3*(size_t)BN;   // BN   (reused per direction)

    hipMemsetAsync(acc, 0, 16*sizeof(float), stream);

    const int threads = 256;
    const int blocks  = (BN + threads - 1) / threads;   // 6144, no tail

    flows_kernel<<<blocks, threads, 0, stream>>>(meanf, log_varf, meanb, log_varb,
                                                 target, noise_f, noise_b,
                                                 flowf, flowb, acc);
    // direction 1: flow_a=flowf, flow_b=flowb, img_a=img1, img_b=img2
    warp_terms_kernel<<<blocks, threads, 0, stream>>>(flowf, flowb, img1, img2, warp, maskb, acc);
    grad_kernel<<<blocks, threads, 0, stream>>>(img1, warp, maskb, acc);
    // direction 2: flow_a=flowb, flow_b=flowf, img_a=img2, img_b=img1
    warp_terms_kernel<<<blocks, threads, 0, stream>>>(flowb, flowf, img2, img1, warp, maskb, acc);
    grad_kernel<<<blocks, threads, 0, stream>>>(img2, warp, maskb, acc);

    finalize_kernel<<<1, 1, 0, stream>>>(acc, (float*)d_out);
}

// Round 2
// 317.787 us; speedup vs baseline: 2.0004x; 2.0004x over previous
//
#include <hip/hip_runtime.h>
#include <math.h>

#define BATCH 8
#define IH 384
#define IW 512
#define NPIX (IH*IW)          // 196608
#define BN (BATCH*NPIX)       // 1572864

// partial-sum layout in d_ws (floats):
//   [0 .. 4*6144)      : energy partials (4 segments of 6144: warp d0, grad d0, warp d1, grad d1)
//   [4*6144 .. +1536)  : entropy partials
//   [.. +1536)         : epe partials
#define NB_SCAL 6144
#define NB_FLOW 1536
#define ENT_OFF (4*NB_SCAL)
#define EPE_OFF (ENT_OFF + NB_FLOW)
#define PART_TOTAL (EPE_OFF + NB_FLOW)

__device__ __forceinline__ float sigmoidf_(float x){ return 1.0f/(1.0f+expf(-x)); }

__device__ __forceinline__ float block_reduce_sum(float v){
    __shared__ float s[8];
    #pragma unroll
    for (int off=32; off>0; off>>=1) v += __shfl_down(v, off);
    int lane = threadIdx.x & 63, wid = threadIdx.x >> 6;
    if (lane==0) s[wid] = v;
    __syncthreads();
    float t = 0.f;
    if (wid==0){
        int nw = (blockDim.x+63)>>6;
        t = (lane < nw) ? s[lane] : 0.f;
        #pragma unroll
        for (int off=4; off>0; off>>=1) t += __shfl_down(t, off);
    }
    __syncthreads();
    return t;
}

// Kernel 1: flows = mean + exp(lv/2)*noise (float4, 4 px/thread); entropy + epe partials.
__global__ __launch_bounds__(256)
void flows_kernel(const float* __restrict__ meanf, const float* __restrict__ log_varf,
                  const float* __restrict__ meanb, const float* __restrict__ log_varb,
                  const float* __restrict__ target,
                  const float* __restrict__ noise_f, const float* __restrict__ noise_b,
                  float* __restrict__ flowf, float* __restrict__ flowb,
                  float* __restrict__ part)
{
    int t = blockIdx.x*blockDim.x + threadIdx.x;      // float4 index over (B, NPIX/4)
    const int NP4 = NPIX/4;
    int b = t / NP4, p4 = t - b*NP4;
    size_t i0 = ((size_t)b*2*NPIX)/4 + p4;            // ch0 float4 idx
    size_t i1 = i0 + NPIX/4;                          // ch1

    const float4* mf = (const float4*)meanf;  const float4* lf = (const float4*)log_varf;
    const float4* mb = (const float4*)meanb;  const float4* lb = (const float4*)log_varb;
    const float4* nf = (const float4*)noise_f; const float4* nb = (const float4*)noise_b;
    const float4* tg = (const float4*)target;
    float4* ff = (float4*)flowf; float4* fb = (float4*)flowb;

    float4 lf0 = lf[i0], lf1 = lf[i1], lb0 = lb[i0], lb1 = lb[i1];
    float4 mf0 = mf[i0], mf1 = mf[i1], mb0 = mb[i0], mb1 = mb[i1];
    float4 nf0 = nf[i0], nf1 = nf[i1], nb0 = nb[i0], nb1 = nb[i1];

    float4 o;
    o.x = mf0.x + expf(0.5f*lf0.x)*nf0.x; o.y = mf0.y + expf(0.5f*lf0.y)*nf0.y;
    o.z = mf0.z + expf(0.5f*lf0.z)*nf0.z; o.w = mf0.w + expf(0.5f*lf0.w)*nf0.w;
    ff[i0] = o;
    o.x = mf1.x + expf(0.5f*lf1.x)*nf1.x; o.y = mf1.y + expf(0.5f*lf1.y)*nf1.y;
    o.z = mf1.z + expf(0.5f*lf1.z)*nf1.z; o.w = mf1.w + expf(0.5f*lf1.w)*nf1.w;
    ff[i1] = o;
    o.x = mb0.x + expf(0.5f*lb0.x)*nb0.x; o.y = mb0.y + expf(0.5f*lb0.y)*nb0.y;
    o.z = mb0.z + expf(0.5f*lb0.z)*nb0.z; o.w = mb0.w + expf(0.5f*lb0.w)*nb0.w;
    fb[i0] = o;
    o.x = mb1.x + expf(0.5f*lb1.x)*nb1.x; o.y = mb1.y + expf(0.5f*lb1.y)*nb1.y;
    o.z = mb1.z + expf(0.5f*lb1.z)*nb1.z; o.w = mb1.w + expf(0.5f*lb1.w)*nb1.w;
    fb[i1] = o;

    float ent = (lf0.x+lf0.y+lf0.z+lf0.w) + (lf1.x+lf1.y+lf1.z+lf1.w)
              + (lb0.x+lb0.y+lb0.z+lb0.w) + (lb1.x+lb1.y+lb1.z+lb1.w);

    float4 t0 = tg[i0], t1 = tg[i1];
    float d0, d1, epe = 0.f;
    d0 = mf0.x - t0.x; d1 = mf1.x - t1.x; epe += sqrtf(d0*d0 + d1*d1);
    d0 = mf0.y - t0.y; d1 = mf1.y - t1.y; epe += sqrtf(d0*d0 + d1*d1);
    d0 = mf0.z - t0.z; d1 = mf1.z - t1.z; epe += sqrtf(d0*d0 + d1*d1);
    d0 = mf0.w - t0.w; d1 = mf1.w - t1.w; epe += sqrtf(d0*d0 + d1*d1);

    float s = block_reduce_sum(ent);
    if (threadIdx.x == 0) part[ENT_OFF + blockIdx.x] = s;
    float s2 = block_reduce_sum(epe);
    if (threadIdx.x == 0) part[EPE_OFF + blockIdx.x] = s2;
}

// Kernel 2: one direction's warp + mask + (mask, data, smooth, fb) terms.
__global__ __launch_bounds__(256)
void warp_terms_kernel(const float* __restrict__ flow_a, const float* __restrict__ flow_b,
                       const float* __restrict__ img_a,  const float* __restrict__ img_b,
                       float* __restrict__ warp_out, float* __restrict__ mask_out,
                       float* __restrict__ part, int seg)
{
    int t = blockIdx.x*blockDim.x + threadIdx.x;
    int b = t / NPIX, p = t - b*NPIX;
    int h = p / IW, w = p - h*IW;
    const float* fa = flow_a + (size_t)b*2*NPIX;
    float fax = fa[p], fay = fa[NPIX + p];

    float Xp = (float)w + fax;
    float Yp = (float)h + fay;
    float mx = sigmoidf_(Xp + 0.5f) * (1.f - sigmoidf_(Xp - ((float)IW - 0.5f)));
    float my = sigmoidf_(Yp + 0.5f) * (1.f - sigmoidf_(Yp - ((float)IH - 0.5f)));
    float bm = mx * my;

    float x0f = floorf(Xp), y0f = floorf(Yp);
    float wx1 = Xp - x0f, wy1 = Yp - y0f;
    float wx0 = 1.f - wx1, wy0 = 1.f - wy1;
    int idx[4]; float wt[4];
    {
        float xs[4] = {x0f, x0f + 1.f, x0f,       x0f + 1.f};
        float ys[4] = {y0f, y0f,       y0f + 1.f, y0f + 1.f};
        float wsx[4] = {wx0*wy0, wx1*wy0, wx0*wy1, wx1*wy1};
        #pragma unroll
        for (int k = 0; k < 4; ++k){
            bool valid = (xs[k] >= 0.f) && (xs[k] <= (float)(IW-1)) &&
                         (ys[k] >= 0.f) && (ys[k] <= (float)(IH-1));
            float xc = fminf(fmaxf(xs[k], 0.f), (float)(IW-1));
            float yc = fminf(fmaxf(ys[k], 0.f), (float)(IH-1));
            idx[k] = (int)yc * IW + (int)xc;
            wt[k]  = valid ? wsx[k] : 0.f;
        }
    }

    const float* fb = flow_b + (size_t)b*2*NPIX;
    float fbwx = wt[0]*fb[idx[0]] + wt[1]*fb[idx[1]] + wt[2]*fb[idx[2]] + wt[3]*fb[idx[3]];
    float fbwy = wt[0]*fb[NPIX+idx[0]] + wt[1]*fb[NPIX+idx[1]]
               + wt[2]*fb[NPIX+idx[2]] + wt[3]*fb[NPIX+idx[3]];

    const float* ib = img_b + (size_t)b*3*NPIX;
    float iw[3];
    #pragma unroll
    for (int c = 0; c < 3; ++c){
        const float* s = ib + (size_t)c*NPIX;
        iw[c] = wt[0]*s[idx[0]] + wt[1]*s[idx[1]] + wt[2]*s[idx[2]] + wt[3]*s[idx[3]];
        warp_out[(size_t)b*3*NPIX + (size_t)c*NPIX + p] = iw[c];
    }

    float mag = fax*fax + fay*fay + fbwx*fbwx + fbwy*fbwy;
    float dfx = fax + fbwx, dfy = fay + fbwy;
    float D = dfx*dfx + dfy*dfy;
    float occ = 1.f - sigmoidf_(D - (0.01f*mag + 0.5f));
    float mask = bm * occ;
    mask_out[t] = mask;

    float local = (1.f - mask);

    const float* ia = img_a + (size_t)b*3*NPIX;
    float A = 0.f;
    #pragma unroll
    for (int c = 0; c < 3; ++c){
        float d = ia[(size_t)c*NPIX + p] - iw[c];
        A += d*d;
    }
    local += sqrtf(A + 1e-5f) * mask;
    local += sqrtf(D + 1e-5f) * mask;

    float Bt = 0.f;
    if (w < IW-1){
        float d0 = fa[p+1] - fax;
        float d1 = fa[NPIX + p+1] - fay;
        Bt += d0*d0 + d1*d1;
    }
    if (h < IH-1){
        float d0 = fa[p+IW] - fax;
        float d1 = fa[NPIX + p+IW] - fay;
        Bt += d0*d0 + d1*d1;
    }
    local += sqrtf(Bt + 1e-5f);

    float s = block_reduce_sum(local);
    if (threadIdx.x == 0) part[seg*NB_SCAL + blockIdx.x] = s;
}

// Kernel 3: gradient-constancy term from materialized warp + mask.
__global__ __launch_bounds__(256)
void grad_kernel(const float* __restrict__ img_a, const float* __restrict__ warp,
                 const float* __restrict__ mask, float* __restrict__ part, int seg)
{
    const float K0 = -1.f/12.f, K1 = 2.f/3.f, K3 = -2.f/3.f, K4 = 1.f/12.f;
    int t = blockIdx.x*blockDim.x + threadIdx.x;
    int b = t / NPIX, p = t - b*NPIX;
    int h = p / IW, w = p - h*IW;
    float Ct = 0.f;
    #pragma unroll
    for (int c = 0; c < 3; ++c){
        const float* A_ = img_a + (size_t)b*3*NPIX + (size_t)c*NPIX;
        const float* W_ = warp  + (size_t)b*3*NPIX + (size_t)c*NPIX;
        float gxa = 0.f, gxw = 0.f;
        if (w >= 2)    { gxa += K0*A_[p-2];    gxw += K0*W_[p-2]; }
        if (w >= 1)    { gxa += K1*A_[p-1];    gxw += K1*W_[p-1]; }
        if (w <= IW-2) { gxa += K3*A_[p+1];    gxw += K3*W_[p+1]; }
        if (w <= IW-3) { gxa += K4*A_[p+2];    gxw += K4*W_[p+2]; }
        float d = gxa - gxw; Ct += d*d;
        float gya = 0.f, gyw = 0.f;
        if (h >= 2)    { gya += K0*A_[p-2*IW]; gyw += K0*W_[p-2*IW]; }
        if (h >= 1)    { gya += K1*A_[p-IW];   gyw += K1*W_[p-IW]; }
        if (h <= IH-2) { gya += K3*A_[p+IW];   gyw += K3*W_[p+IW]; }
        if (h <= IH-3) { gya += K4*A_[p+2*IW]; gyw += K4*W_[p+2*IW]; }
        d = gya - gyw; Ct += d*d;
    }
    float local = sqrtf(Ct + 1e-5f) * mask[t];
    float s = block_reduce_sum(local);
    if (threadIdx.x == 0) part[seg*NB_SCAL + blockIdx.x] = s;
}

// Finalize: reduce all partials with one block.
__global__ __launch_bounds__(256)
void finalize_kernel(const float* __restrict__ part, float* __restrict__ out)
{
    float e = 0.f, ent = 0.f, epe = 0.f;
    for (int i = threadIdx.x; i < 4*NB_SCAL; i += 256) e += part[i];
    for (int i = threadIdx.x; i < NB_FLOW; i += 256){
        ent += part[ENT_OFF + i];
        epe += part[EPE_OFF + i];
    }
    e   = block_reduce_sum(e);
    ent = block_reduce_sum(ent);
    epe = block_reduce_sum(epe);
    if (threadIdx.x == 0){
        out[0] = e / (float)BATCH - ent / (2.f * (float)BATCH);
        out[1] = epe / ((float)BATCH * (float)NPIX);
    }
}

extern "C" void kernel_launch(void* const* d_in, const int* in_sizes, int n_in,
                              void* d_out, int out_size, void* d_ws, size_t ws_size,
                              hipStream_t stream)
{
    const float* meanf    = (const float*)d_in[0];
    const float* log_varf = (const float*)d_in[1];
    const float* meanb    = (const float*)d_in[2];
    const float* log_varb = (const float*)d_in[3];
    const float* img1     = (const float*)d_in[4];
    const float* img2     = (const float*)d_in[5];
    const float* target   = (const float*)d_in[6];
    const float* noise_f  = (const float*)d_in[7];
    const float* noise_b  = (const float*)d_in[8];

    float* ws    = (float*)d_ws;
    float* part  = ws;                       // PART_TOTAL floats (~28K), all written unconditionally
    float* flowf = ws + 32768;               // 2*BN
    float* flowb = flowf + 2*(size_t)BN;     // 2*BN
    float* warp  = flowb + 2*(size_t)BN;     // 3*BN (reused per direction)
    float* maskb = warp  + 3*(size_t)BN;     // BN   (reused per direction)

    const int threads = 256;

    flows_kernel<<<NB_FLOW, threads, 0, stream>>>(meanf, log_varf, meanb, log_varb,
                                                  target, noise_f, noise_b,
                                                  flowf, flowb, part);
    warp_terms_kernel<<<NB_SCAL, threads, 0, stream>>>(flowf, flowb, img1, img2, warp, maskb, part, 0);
    grad_kernel<<<NB_SCAL, threads, 0, stream>>>(img1, warp, maskb, part, 1);
    warp_terms_kernel<<<NB_SCAL, threads, 0, stream>>>(flowb, flowf, img2, img1, warp, maskb, part, 2);
    grad_kernel<<<NB_SCAL, threads, 0, stream>>>(img2, warp, maskb, part, 3);

    finalize_kernel<<<1, threads, 0, stream>>>(part, (float*)d_out);
}

// Round 3
// 264.177 us; speedup vs baseline: 2.4064x; 1.2029x over previous
//
#include <hip/hip_runtime.h>
#include <math.h>

#define BATCH 8
#define IH 384
#define IW 512
#define NPIX (IH*IW)          // 196608
#define BN (BATCH*NPIX)       // 1572864

// Fused-kernel tiling: 64x16 output tile, +2 halo each side for the 5-tap filter
#define TW 64
#define TH 16
#define RW (TW+4)             // 68
#define RH (TH+4)             // 20
#define RN (RW*RH)            // 1360
#define NTX (IW/TW)           // 8
#define NTY (IH/TH)           // 24
#define NB_DIR (NTX*NTY*BATCH*2)   // 3072

#define NB_FLOW 1536
#define ENT_OFF NB_DIR                 // 3072
#define EPE_OFF (ENT_OFF + NB_FLOW)    // 4608
#define PART_FLOATS 8192

__device__ __forceinline__ float frcp_(float x){ return __builtin_amdgcn_rcpf(x); }
__device__ __forceinline__ float fsqrt_(float x){ return __builtin_amdgcn_sqrtf(x); }
__device__ __forceinline__ float sigmoidf_(float x){ return frcp_(1.0f + __expf(-x)); }

__device__ __forceinline__ float block_reduce_sum(float v){
    __shared__ float s[8];
    #pragma unroll
    for (int off=32; off>0; off>>=1) v += __shfl_down(v, off);
    int lane = threadIdx.x & 63, wid = threadIdx.x >> 6;
    if (lane==0) s[wid] = v;
    __syncthreads();
    float t = 0.f;
    if (wid==0){
        int nw = (blockDim.x+63)>>6;
        t = (lane < nw) ? s[lane] : 0.f;
        #pragma unroll
        for (int off=4; off>0; off>>=1) t += __shfl_down(t, off);
    }
    __syncthreads();
    return t;
}

// Kernel 1: flows = mean + exp(lv/2)*noise (float4); entropy + epe partials.
__global__ __launch_bounds__(256)
void flows_kernel(const float* __restrict__ meanf, const float* __restrict__ log_varf,
                  const float* __restrict__ meanb, const float* __restrict__ log_varb,
                  const float* __restrict__ target,
                  const float* __restrict__ noise_f, const float* __restrict__ noise_b,
                  float* __restrict__ flowf, float* __restrict__ flowb,
                  float* __restrict__ part)
{
    int t = blockIdx.x*blockDim.x + threadIdx.x;      // float4 index over (B, NPIX/4)
    const int NP4 = NPIX/4;
    int b = t / NP4, p4 = t - b*NP4;
    size_t i0 = ((size_t)b*2*NPIX)/4 + p4;            // ch0 float4 idx
    size_t i1 = i0 + NPIX/4;                          // ch1

    const float4* mf = (const float4*)meanf;  const float4* lf = (const float4*)log_varf;
    const float4* mb = (const float4*)meanb;  const float4* lb = (const float4*)log_varb;
    const float4* nf = (const float4*)noise_f; const float4* nb = (const float4*)noise_b;
    const float4* tg = (const float4*)target;
    float4* ff = (float4*)flowf; float4* fbp = (float4*)flowb;

    float4 lf0 = lf[i0], lf1 = lf[i1], lb0 = lb[i0], lb1 = lb[i1];
    float4 mf0 = mf[i0], mf1 = mf[i1], mb0 = mb[i0], mb1 = mb[i1];
    float4 nf0 = nf[i0], nf1 = nf[i1], nb0 = nb[i0], nb1 = nb[i1];

    float4 o;
    o.x = mf0.x + __expf(0.5f*lf0.x)*nf0.x; o.y = mf0.y + __expf(0.5f*lf0.y)*nf0.y;
    o.z = mf0.z + __expf(0.5f*lf0.z)*nf0.z; o.w = mf0.w + __expf(0.5f*lf0.w)*nf0.w;
    ff[i0] = o;
    o.x = mf1.x + __expf(0.5f*lf1.x)*nf1.x; o.y = mf1.y + __expf(0.5f*lf1.y)*nf1.y;
    o.z = mf1.z + __expf(0.5f*lf1.z)*nf1.z; o.w = mf1.w + __expf(0.5f*lf1.w)*nf1.w;
    ff[i1] = o;
    o.x = mb0.x + __expf(0.5f*lb0.x)*nb0.x; o.y = mb0.y + __expf(0.5f*lb0.y)*nb0.y;
    o.z = mb0.z + __expf(0.5f*lb0.z)*nb0.z; o.w = mb0.w + __expf(0.5f*lb0.w)*nb0.w;
    fbp[i0] = o;
    o.x = mb1.x + __expf(0.5f*lb1.x)*nb1.x; o.y = mb1.y + __expf(0.5f*lb1.y)*nb1.y;
    o.z = mb1.z + __expf(0.5f*lb1.z)*nb1.z; o.w = mb1.w + __expf(0.5f*lb1.w)*nb1.w;
    fbp[i1] = o;

    float ent = (lf0.x+lf0.y+lf0.z+lf0.w) + (lf1.x+lf1.y+lf1.z+lf1.w)
              + (lb0.x+lb0.y+lb0.z+lb0.w) + (lb1.x+lb1.y+lb1.z+lb1.w);

    float4 t0 = tg[i0], t1 = tg[i1];
    float d0, d1, epe = 0.f;
    d0 = mf0.x - t0.x; d1 = mf1.x - t1.x; epe += fsqrt_(d0*d0 + d1*d1);
    d0 = mf0.y - t0.y; d1 = mf1.y - t1.y; epe += fsqrt_(d0*d0 + d1*d1);
    d0 = mf0.z - t0.z; d1 = mf1.z - t1.z; epe += fsqrt_(d0*d0 + d1*d1);
    d0 = mf0.w - t0.w; d1 = mf1.w - t1.w; epe += fsqrt_(d0*d0 + d1*d1);

    float s = block_reduce_sum(ent);
    if (threadIdx.x == 0) part[ENT_OFF + blockIdx.x] = s;
    float s2 = block_reduce_sum(epe);
    if (threadIdx.x == 0) part[EPE_OFF + blockIdx.x] = s2;
}

// Fused kernel: one 64x16 tile of one direction.
// Phase A: warp img_b by flow_a over tile+halo into LDS; interior pixels also
//          compute mask/data/fb/smooth terms (mask stored in LDS).
// Phase B: gradient-constancy term from LDS warp + global img_a stencil.
__global__ __launch_bounds__(256)
void dir_kernel(const float* __restrict__ flowf, const float* __restrict__ flowb,
                const float* __restrict__ img1, const float* __restrict__ img2,
                float* __restrict__ part)
{
    __shared__ float wlds[3][RH][RW];   // warped img_b (0 outside image)
    __shared__ float mlds[TH][TW];      // mask

    const int dir = blockIdx.z & 1, b = blockIdx.z >> 1;
    const float *pfa, *pfb, *pia, *pib;
    if (dir == 0){ pfa = flowf; pfb = flowb; pia = img1; pib = img2; }
    else         { pfa = flowb; pfb = flowf; pia = img2; pib = img1; }
    pfa += (size_t)b*2*NPIX; pfb += (size_t)b*2*NPIX;
    pia += (size_t)b*3*NPIX; pib += (size_t)b*3*NPIX;

    const int tw0 = blockIdx.x*TW, th0 = blockIdx.y*TH;
    const int tid = threadIdx.x;
    float local = 0.f;

    // ---- Phase A ----
    for (int i = tid; i < RN; i += 256){
        int hh = i / RW, ww = i - hh*RW;
        int gh = th0 + hh - 2, gw = tw0 + ww - 2;
        bool inimg = (gh >= 0) && (gh < IH) && (gw >= 0) && (gw < IW);
        float w0 = 0.f, w1 = 0.f, w2 = 0.f;
        if (inimg){
            int p = gh*IW + gw;
            float fax = pfa[p], fay = pfa[NPIX + p];
            float Xp = (float)gw + fax;
            float Yp = (float)gh + fay;

            float x0f = floorf(Xp), y0f = floorf(Yp);
            float wx1 = Xp - x0f, wy1 = Yp - y0f;
            float wx0 = 1.f - wx1, wy0 = 1.f - wy1;
            int idx[4]; float wt[4];
            {
                float xs[4] = {x0f, x0f + 1.f, x0f,       x0f + 1.f};
                float ys[4] = {y0f, y0f,       y0f + 1.f, y0f + 1.f};
                float wsx[4] = {wx0*wy0, wx1*wy0, wx0*wy1, wx1*wy1};
                #pragma unroll
                for (int k = 0; k < 4; ++k){
                    bool valid = (xs[k] >= 0.f) && (xs[k] <= (float)(IW-1)) &&
                                 (ys[k] >= 0.f) && (ys[k] <= (float)(IH-1));
                    float xc = fminf(fmaxf(xs[k], 0.f), (float)(IW-1));
                    float yc = fminf(fmaxf(ys[k], 0.f), (float)(IH-1));
                    idx[k] = (int)yc * IW + (int)xc;
                    wt[k]  = valid ? wsx[k] : 0.f;
                }
            }

            // warp img_b (3 ch)
            w0 = wt[0]*pib[idx[0]] + wt[1]*pib[idx[1]] + wt[2]*pib[idx[2]] + wt[3]*pib[idx[3]];
            {
                const float* s1 = pib + NPIX;
                const float* s2 = pib + 2*NPIX;
                w1 = wt[0]*s1[idx[0]] + wt[1]*s1[idx[1]] + wt[2]*s1[idx[2]] + wt[3]*s1[idx[3]];
                w2 = wt[0]*s2[idx[0]] + wt[1]*s2[idx[1]] + wt[2]*s2[idx[2]] + wt[3]*s2[idx[3]];
            }

            bool interior = (hh >= 2) && (hh < RH-2) && (ww >= 2) && (ww < RW-2);
            if (interior){
                // border mask
                float mx = sigmoidf_(Xp + 0.5f) * (1.f - sigmoidf_(Xp - ((float)IW - 0.5f)));
                float my = sigmoidf_(Yp + 0.5f) * (1.f - sigmoidf_(Yp - ((float)IH - 0.5f)));
                float bm = mx * my;

                // flow_b warped
                float fbwx = wt[0]*pfb[idx[0]] + wt[1]*pfb[idx[1]] + wt[2]*pfb[idx[2]] + wt[3]*pfb[idx[3]];
                const float* pfb1 = pfb + NPIX;
                float fbwy = wt[0]*pfb1[idx[0]] + wt[1]*pfb1[idx[1]] + wt[2]*pfb1[idx[2]] + wt[3]*pfb1[idx[3]];

                float mag = fax*fax + fay*fay + fbwx*fbwx + fbwy*fbwy;
                float dfx = fax + fbwx, dfy = fay + fbwy;
                float D = dfx*dfx + dfy*dfy;
                float occ = 1.f - sigmoidf_(D - (0.01f*mag + 0.5f));
                float mask = bm * occ;
                mlds[hh-2][ww-2] = mask;

                local += (1.f - mask);                       // mask term

                float d0 = pia[p]        - w0;               // data term
                float d1 = pia[NPIX+p]   - w1;
                float d2 = pia[2*NPIX+p] - w2;
                local += fsqrt_(d0*d0 + d1*d1 + d2*d2 + 1e-5f) * mask;

                local += fsqrt_(D + 1e-5f) * mask;           // fb term

                float Bt = 0.f;                              // smoothness
                if (gw < IW-1){
                    float e0 = pfa[p+1] - fax;
                    float e1 = pfa[NPIX + p+1] - fay;
                    Bt += e0*e0 + e1*e1;
                }
                if (gh < IH-1){
                    float e0 = pfa[p+IW] - fax;
                    float e1 = pfa[NPIX + p+IW] - fay;
                    Bt += e0*e0 + e1*e1;
                }
                local += fsqrt_(Bt + 1e-5f);
            }
        }
        wlds[0][hh][ww] = w0;
        wlds[1][hh][ww] = w1;
        wlds[2][hh][ww] = w2;
    }
    __syncthreads();

    // ---- Phase B: gradient-constancy ----
    const float K0 = -1.f/12.f, K1 = 2.f/3.f, K3 = -2.f/3.f, K4 = 1.f/12.f;
    for (int i = tid; i < TW*TH; i += 256){
        int hh = i >> 6, ww = i & 63;       // TW=64
        int gh = th0 + hh, gw = tw0 + ww;
        int lh = hh + 2, lw = ww + 2;
        int p = gh*IW + gw;
        float Ct = 0.f;
        #pragma unroll
        for (int c = 0; c < 3; ++c){
            const float* A_ = pia + (size_t)c*NPIX;
            float gxa = 0.f;
            if (gw >= 2)    gxa += K0*A_[p-2];
            if (gw >= 1)    gxa += K1*A_[p-1];
            if (gw <= IW-2) gxa += K3*A_[p+1];
            if (gw <= IW-3) gxa += K4*A_[p+2];
            float gxw = K0*wlds[c][lh][lw-2] + K1*wlds[c][lh][lw-1]
                      + K3*wlds[c][lh][lw+1] + K4*wlds[c][lh][lw+2];
            float d = gxa - gxw; Ct += d*d;
            float gya = 0.f;
            if (gh >= 2)    gya += K0*A_[p-2*IW];
            if (gh >= 1)    gya += K1*A_[p-IW];
            if (gh <= IH-2) gya += K3*A_[p+IW];
            if (gh <= IH-3) gya += K4*A_[p+2*IW];
            float gyw = K0*wlds[c][lh-2][lw] + K1*wlds[c][lh-1][lw]
                      + K3*wlds[c][lh+1][lw] + K4*wlds[c][lh+2][lw];
            d = gya - gyw; Ct += d*d;
        }
        local += fsqrt_(Ct + 1e-5f) * mlds[hh][ww];
    }

    float s = block_reduce_sum(local);
    if (tid == 0) part[blockIdx.x + NTX*(blockIdx.y + NTY*blockIdx.z)] = s;
}

// Finalize: reduce all partials with one block.
__global__ __launch_bounds__(256)
void finalize_kernel(const float* __restrict__ part, float* __restrict__ out)
{
    float e = 0.f, ent = 0.f, epe = 0.f;
    for (int i = threadIdx.x; i < NB_DIR; i += 256) e += part[i];
    for (int i = threadIdx.x; i < NB_FLOW; i += 256){
        ent += part[ENT_OFF + i];
        epe += part[EPE_OFF + i];
    }
    e   = block_reduce_sum(e);
    ent = block_reduce_sum(ent);
    epe = block_reduce_sum(epe);
    if (threadIdx.x == 0){
        out[0] = e / (float)BATCH - ent / (2.f * (float)BATCH);
        out[1] = epe / ((float)BATCH * (float)NPIX);
    }
}

extern "C" void kernel_launch(void* const* d_in, const int* in_sizes, int n_in,
                              void* d_out, int out_size, void* d_ws, size_t ws_size,
                              hipStream_t stream)
{
    const float* meanf    = (const float*)d_in[0];
    const float* log_varf = (const float*)d_in[1];
    const float* meanb    = (const float*)d_in[2];
    const float* log_varb = (const float*)d_in[3];
    const float* img1     = (const float*)d_in[4];
    const float* img2     = (const float*)d_in[5];
    const float* target   = (const float*)d_in[6];
    const float* noise_f  = (const float*)d_in[7];
    const float* noise_b  = (const float*)d_in[8];

    float* ws    = (float*)d_ws;
    float* part  = ws;                         // PART_FLOATS floats
    float* flowf = ws + PART_FLOATS;           // 2*BN
    float* flowb = flowf + 2*(size_t)BN;       // 2*BN

    const int threads = 256;

    flows_kernel<<<NB_FLOW, threads, 0, stream>>>(meanf, log_varf, meanb, log_varb,
                                                  target, noise_f, noise_b,
                                                  flowf, flowb, part);

    dim3 grid(NTX, NTY, BATCH*2);
    dir_kernel<<<grid, threads, 0, stream>>>(flowf, flowb, img1, img2, part);

    finalize_kernel<<<1, threads, 0, stream>>>(part, (float*)d_out);
}